// Round 15
// baseline (160.393 us; speedup 1.0000x reference)
//
#include <hip/hip_runtime.h>
#include <cstdint>
#include <cmath>

typedef _Float16 half8 __attribute__((ext_vector_type(8)));
typedef unsigned short ushort8 __attribute__((ext_vector_type(8)));
typedef float floatx4 __attribute__((ext_vector_type(4)));

#define VT_STRIDE 2080  // 2048 + 32: breaks 4KB L2 set aliasing on V^T rows

__device__ __forceinline__ unsigned short f2h(float f) {
    union { _Float16 h; unsigned short u; } cv;
    cv.h = (_Float16)f;
    return cv.u;
}

// async global -> LDS, 16B per lane; LDS dest is wave-uniform base + lane*16
__device__ __forceinline__ void gld_lds16(const unsigned short* g, unsigned short* l) {
    __builtin_amdgcn_global_load_lds(
        (const __attribute__((address_space(1))) unsigned int*)g,
        (__attribute__((address_space(3))) unsigned int*)l, 16, 0, 0);
}

// ---------------- merged prep: cast x (fp32->fp16) + transpose+cast W matrices ----------------
__global__ void prep_kernel(const float* __restrict__ x,
                            const float* __restrict__ Wq, const float* __restrict__ Wkv,
                            const float* __restrict__ Wout,
                            unsigned short* __restrict__ xh,
                            unsigned short* __restrict__ Wqkvt, unsigned short* __restrict__ Wot) {
    int bxi = blockIdx.x;
    if (bxi >= 68) {
        int fb = (bxi - 68) * 32 + blockIdx.y;          // 0..2047
        int tt = threadIdx.y * 32 + threadIdx.x;        // 0..255
        int idx = fb * 256 + tt;                        // < 524288
        const float4* p = (const float4*)x;
        float4 a = p[idx * 2], b = p[idx * 2 + 1];
        ushort8 o;
        o[0] = f2h(a.x); o[1] = f2h(a.y); o[2] = f2h(a.z); o[3] = f2h(a.w);
        o[4] = f2h(b.x); o[5] = f2h(b.y); o[6] = f2h(b.z); o[7] = f2h(b.w);
        *(ushort8*)(xh + (size_t)idx * 8) = o;
        return;
    }
    __shared__ float tile[32][33];
    const float* in; unsigned short* out; int C; int cb;
    if (bxi < 32)      { in = Wq;   out = Wqkvt;                 C = 1024; cb = bxi; }
    else if (bxi < 36) { in = Wkv;  out = Wqkvt + 1024 * 1024;   C = 128;  cb = bxi - 32; }
    else               { in = Wout; out = Wot;                   C = 1024; cb = bxi - 36; }
    int bx = cb * 32, by = blockIdx.y * 32;
    int xx = threadIdx.x, y0 = threadIdx.y;
    #pragma unroll
    for (int k = 0; k < 4; k++) {
        int y = y0 + k * 8;
        tile[y][xx] = in[(size_t)(by + y) * C + bx + xx];
    }
    __syncthreads();
    #pragma unroll
    for (int k = 0; k < 4; k++) {
        int y = y0 + k * 8;
        out[(size_t)(bx + y) * 1024 + by + xx] = f2h(tile[xx][y]);
    }
}

// ---------------- GEMM 64M x 128N, K=1024 (R5/R8-measured best, byte-exact) ----------------
template<int MODE>
__global__ __launch_bounds__(256) void gemm_mn(
    const unsigned short* __restrict__ A, const unsigned short* __restrict__ Bt,
    unsigned short* __restrict__ oq, unsigned short* __restrict__ ok,
    unsigned short* __restrict__ ov, float* __restrict__ of,
    const float* __restrict__ bias)
{
    __shared__ __align__(16) unsigned short As[2][64 * 64];
    __shared__ __align__(16) unsigned short Bs[2][128 * 64];
    const int K = 1024;
    int t = threadIdx.x;
    int w = t >> 6, lane = t & 63, g = lane >> 4, il = lane & 15;
    int wr = w >> 1, wc = w & 1;
    int m0 = blockIdx.x * 64, n0 = blockIdx.y * 128;

    int l8 = lane >> 3, b8 = lane & 7;
    int swz = (b8 ^ l8) * 8;
    const unsigned short* Ag = A  + (size_t)(m0 + w * 16 + l8) * K + swz;
    const unsigned short* Bg = Bt + (size_t)(n0 + w * 32 + l8) * K + swz;
    int e0 = (g ^ (il & 7)) * 8;

    floatx4 acc[2][4] = {};

    #pragma unroll
    for (int q = 0; q < 2; q++)
        gld_lds16(Ag + (size_t)(q * 8) * K, &As[0][(w * 16 + q * 8) * 64]);
    #pragma unroll
    for (int q = 0; q < 4; q++)
        gld_lds16(Bg + (size_t)(q * 8) * K, &Bs[0][(w * 32 + q * 8) * 64]);

    int cb = 0;
    for (int k0 = 0; k0 < K; k0 += 64, cb ^= 1) {
        if (k0 + 64 < K) {
            #pragma unroll
            for (int q = 0; q < 2; q++)
                gld_lds16(Ag + (size_t)(q * 8) * K + k0 + 64, &As[cb ^ 1][(w * 16 + q * 8) * 64]);
            #pragma unroll
            for (int q = 0; q < 4; q++)
                gld_lds16(Bg + (size_t)(q * 8) * K + k0 + 64, &Bs[cb ^ 1][(w * 32 + q * 8) * 64]);
            asm volatile("s_waitcnt vmcnt(6)" ::: "memory");
        } else {
            asm volatile("s_waitcnt vmcnt(0)" ::: "memory");
        }
        __builtin_amdgcn_s_barrier();
        __builtin_amdgcn_sched_barrier(0);

        const unsigned short* Ac = &As[cb][0];
        const unsigned short* Bc = &Bs[cb][0];
        #pragma unroll
        for (int ks = 0; ks < 2; ks++) {
            half8 a[2];
            #pragma unroll
            for (int mt = 0; mt < 2; mt++)
                a[mt] = *(const half8*)&Ac[(wr * 32 + mt * 16 + il) * 64 + (e0 ^ (ks * 32))];
            #pragma unroll
            for (int nt = 0; nt < 4; nt++) {
                half8 b = *(const half8*)&Bc[(wc * 64 + nt * 16 + il) * 64 + (e0 ^ (ks * 32))];
                #pragma unroll
                for (int mt = 0; mt < 2; mt++)
                    acc[mt][nt] = __builtin_amdgcn_mfma_f32_16x16x32_f16(a[mt], b, acc[mt][nt], 0, 0, 0);
            }
        }
        asm volatile("s_waitcnt lgkmcnt(0)" ::: "memory");
        __builtin_amdgcn_s_barrier();
    }

    #pragma unroll
    for (int mt = 0; mt < 2; mt++) {
        #pragma unroll
        for (int nt = 0; nt < 4; nt++) {
            #pragma unroll
            for (int r = 0; r < 4; r++) {
                int row = m0 + wr * 32 + mt * 16 + 4 * g + r;
                int col = n0 + wc * 64 + nt * 16 + il;
                float v = acc[mt][nt][r];
                if (MODE == 0) {
                    if (col < 1024) {
                        int b = row >> 11, i = row & 2047, h = col >> 6, d = col & 63;
                        oq[(size_t)((b * 16 + h) * 2048 + i) * 64 + d] = f2h(v * 0.18033688011112042f);
                    } else if (col < 1088) {
                        ok[(size_t)row * 64 + (col - 1024)] = f2h(v);
                    } else {
                        int b = row >> 11, j = row & 2047;
                        ov[(size_t)((b << 6) + (col - 1088)) * VT_STRIDE + j] = f2h(v);
                    }
                } else {
                    of[(size_t)row * 1024 + col] = v + bias[col];
                }
            }
        }
    }
}

// ---------------- flash attention: single-buffered K AND V (R12-measured best) ----------------
// LDS 26624B. Grid (32 bh fast, 32 tiles, balanced permutation {31-j, j, 23-j, 8+j}).
// Per chunk: QK^T reads K frags, V frags -> regs, lgkmcnt(0)+raw barrier (all buffer
// reads retired), THEN stage K(c+1)+V(c+1) -- DMA flies under softmax+pack+PV; the
// loop-top __syncthreads drains vmcnt(0) before the buffers are read again.
__global__ __launch_bounds__(256) void attn_kernel(
    const unsigned short* __restrict__ qh, const unsigned short* __restrict__ kh,
    const unsigned short* __restrict__ vt, const float* __restrict__ rel_emb,
    unsigned short* __restrict__ ob)
{
    __shared__ float bias_tab[256];
    __shared__ __align__(16) unsigned short Ks[64 * 64];      // [j][d], single-buffered
    __shared__ __align__(16) unsigned short Vs[64 * 64];      // [d][j], single-buffered
    __shared__ __align__(16) unsigned short Pl[64 * 72];      // wave-private P rows

    int yy = blockIdx.y;
    int jp = yy & 7, sp = yy >> 3;   // balanced tile permutation
    int bx = (sp == 0) ? (31 - jp) : (sp == 1) ? jp : (sp == 2) ? (23 - jp) : (8 + jp);
    int bh = blockIdx.x;
    int b = bh >> 4, h = bh & 15;
    int t = threadIdx.x;
    int w = t >> 6, lane = t & 63, g = lane >> 4, il = lane & 15;

    {
        int dlt = t;
        int bucket;
        if (dlt < 16) bucket = dlt;
        else {
            float lg = logf((float)dlt * 0.0625f) / 2.0794415416798357f;
            int vv = 16 + (int)(lg * 16.0f);
            bucket = vv < 31 ? vv : 31;
        }
        bias_tab[dlt] = rel_emb[bucket * 16 + h] * 11.541560327111708f;
    }
    float cb31 = rel_emb[31 * 16 + h] * 11.541560327111708f;

    const unsigned short* kbase = kh + (size_t)b * (2048 * 64);
    const unsigned short* vbase = vt + (size_t)b * (64 * VT_STRIDE);
    int prow = (w * 16 + il) * 72;

    int l8 = lane >> 3, b8 = lane & 7;
    int swz = (b8 ^ l8) * 8;
    const unsigned short* kg_base = kbase + (size_t)(w * 16 + l8) * 64 + swz;
    const unsigned short* vg_base = vbase + (size_t)(w * 16 + l8) * VT_STRIDE + swz;
    int e0 = (g ^ (il & 7)) * 8;

    int iw = bx * 64 + w * 16;
    int i_glob = iw + il;
    const unsigned short* qrow = qh + (size_t)(bh * 2048 + i_glob) * 64;
    half8 qf0 = *(const half8*)(qrow + g * 8);
    half8 qf1 = *(const half8*)(qrow + 32 + g * 8);
    floatx4 O[4] = {};
    float m_run = -1e30f, l_run = 0.0f;

    // prologue: stage chunk 0
    gld_lds16(kg_base,                 &Ks[(w * 16) * 64]);
    gld_lds16(kg_base + 8 * 64,        &Ks[(w * 16 + 8) * 64]);
    gld_lds16(vg_base,                 &Vs[(w * 16) * 64]);
    gld_lds16(vg_base + 8 * VT_STRIDE, &Vs[(w * 16 + 8) * 64]);

    for (int c = 0; c <= bx; c++) {
        __syncthreads();   // drains vmcnt(0): K(c)+V(c) staged; lgkm: prior Pl reads retired
        int j0 = c * 64;

        // S^T = K.Q^T from single K buffer
        floatx4 S[4] = {};
        #pragma unroll
        for (int jt = 0; jt < 4; jt++) {
            half8 k0 = *(const half8*)&Ks[jt * 1024 + il * 64 + e0];
            half8 k1 = *(const half8*)&Ks[jt * 1024 + il * 64 + (e0 ^ 32)];
            S[jt] = __builtin_amdgcn_mfma_f32_16x16x32_f16(k0, qf0, S[jt], 0, 0, 0);
            S[jt] = __builtin_amdgcn_mfma_f32_16x16x32_f16(k1, qf1, S[jt], 0, 0, 0);
        }
        // V fragments -> registers
        half8 vf[8];
        #pragma unroll
        for (int ks = 0; ks < 2; ks++)
            #pragma unroll
            for (int dt = 0; dt < 4; dt++)
                vf[ks * 4 + dt] = *(const half8*)&Vs[dt * 1024 + il * 64 + (e0 ^ (ks * 32))];

        // all reads of Ks/Vs retired across the block -> safe to overwrite
        asm volatile("s_waitcnt lgkmcnt(0)" ::: "memory");
        __builtin_amdgcn_s_barrier();
        if (c < bx) {      // stage K(c+1)+V(c+1); DMA flies under softmax+pack+PV
            const unsigned short* kg = kg_base + (size_t)(c + 1) * 4096;
            const unsigned short* vg = vg_base + (c + 1) * 64;
            gld_lds16(kg,                 &Ks[(w * 16) * 64]);
            gld_lds16(kg + 8 * 64,        &Ks[(w * 16 + 8) * 64]);
            gld_lds16(vg,                 &Vs[(w * 16) * 64]);
            gld_lds16(vg + 8 * VT_STRIDE, &Vs[(w * 16 + 8) * 64]);
        }

        float s[16];
        if (c + 3 <= bx) {
            #pragma unroll
            for (int q2 = 0; q2 < 16; q2++) s[q2] = S[q2 >> 2][q2 & 3] + cb31;
        } else if (c < bx) {
            #pragma unroll
            for (int jt = 0; jt < 4; jt++)
                #pragma unroll
                for (int r = 0; r < 4; r++)
                    s[jt * 4 + r] = S[jt][r] + bias_tab[i_glob - (j0 + jt * 16 + 4 * g + r)];
        } else {
            #pragma unroll
            for (int jt = 0; jt < 4; jt++) {
                #pragma unroll
                for (int r = 0; r < 4; r++) {
                    int delta = i_glob - (j0 + jt * 16 + 4 * g + r);
                    int di = delta > 0 ? delta : 0;
                    s[jt * 4 + r] = (delta >= 0) ? (S[jt][r] + bias_tab[di]) : -1e30f;
                }
            }
        }
        // online softmax (exp2 domain), tree reductions, unconditional rescale
        float m8[8];
        #pragma unroll
        for (int q2 = 0; q2 < 8; q2++) m8[q2] = fmaxf(s[q2], s[q2 + 8]);
        #pragma unroll
        for (int q2 = 0; q2 < 4; q2++) m8[q2] = fmaxf(m8[q2], m8[q2 + 4]);
        float mx = fmaxf(fmaxf(m8[0], m8[1]), fmaxf(m8[2], m8[3]));
        mx = fmaxf(mx, __shfl_xor(mx, 16));
        mx = fmaxf(mx, __shfl_xor(mx, 32));
        float m_new = fmaxf(m_run, mx);
        float alpha = __builtin_amdgcn_exp2f(m_run - m_new);
        float p[16];
        #pragma unroll
        for (int q2 = 0; q2 < 16; q2++) p[q2] = __builtin_amdgcn_exp2f(s[q2] - m_new);
        float ps[8];
        #pragma unroll
        for (int q2 = 0; q2 < 8; q2++) ps[q2] = p[q2] + p[q2 + 8];
        #pragma unroll
        for (int q2 = 0; q2 < 4; q2++) ps[q2] += ps[q2 + 4];
        float psum = (ps[0] + ps[1]) + (ps[2] + ps[3]);
        psum += __shfl_xor(psum, 16);
        psum += __shfl_xor(psum, 32);
        l_run = l_run * alpha + psum;
        m_run = m_new;
        float arow[4];
        #pragma unroll
        for (int r = 0; r < 4; r++) arow[r] = __shfl(alpha, 4 * g + r);
        #pragma unroll
        for (int dt = 0; dt < 4; dt++)
            #pragma unroll
            for (int r = 0; r < 4; r++) O[dt][r] *= arow[r];

        #pragma unroll
        for (int jt = 0; jt < 4; jt++) {
            uint2 u;
            u.x = (unsigned int)f2h(p[jt * 4 + 0]) | ((unsigned int)f2h(p[jt * 4 + 1]) << 16);
            u.y = (unsigned int)f2h(p[jt * 4 + 2]) | ((unsigned int)f2h(p[jt * 4 + 3]) << 16);
            *(uint2*)&Pl[prow + jt * 16 + 4 * g] = u;
        }
        #pragma unroll
        for (int ks = 0; ks < 2; ks++) {
            half8 pf = *(const half8*)&Pl[prow + ks * 32 + g * 8];
            #pragma unroll
            for (int dt = 0; dt < 4; dt++)
                O[dt] = __builtin_amdgcn_mfma_f32_16x16x32_f16(pf, vf[ks * 4 + dt], O[dt], 0, 0, 0);
        }
    }
    // epilogue: normalize, store [b*2048+i][h*64+d] fp16
    float inv[4];
    #pragma unroll
    for (int r = 0; r < 4; r++) inv[r] = 1.0f / __shfl(l_run, 4 * g + r);
    #pragma unroll
    for (int dt = 0; dt < 4; dt++) {
        #pragma unroll
        for (int r = 0; r < 4; r++) {
            int i = iw + 4 * g + r;
            int d = dt * 16 + il;
            ob[(size_t)(b * 2048 + i) * 1024 + h * 64 + d] = f2h(O[dt][r] * inv[r]);
        }
    }
}

extern "C" void kernel_launch(void* const* d_in, const int* in_sizes, int n_in,
                              void* d_out, int out_size, void* d_ws, size_t ws_size,
                              hipStream_t stream) {
    const float* x    = (const float*)d_in[0];
    const float* Wq   = (const float*)d_in[1];
    const float* Wkv  = (const float*)d_in[2];
    const float* Wout = (const float*)d_in[3];
    const float* bout = (const float*)d_in[4];
    const float* rel  = (const float*)d_in[5];
    float* out = (float*)d_out;

    unsigned short* ws    = (unsigned short*)d_ws;
    unsigned short* xh    = ws;                      // [4096][1024] fp16 x; reused as attn out
    unsigned short* qh    = xh + 4194304;            // [b,h,i,d] fp16, exp2-domain prescaled
    unsigned short* kh    = qh + 4194304;            // [b*2048+j][64]
    unsigned short* vt    = kh + 262144;             // [b][64][VT_STRIDE] padded V^T
    unsigned short* Wqkvt = vt + 2 * 64 * VT_STRIDE; // [1152][1024]
    unsigned short* Wot   = Wqkvt + 1179648;         // [1024][1024]
    unsigned short* ob    = xh;

    prep_kernel<<<dim3(132, 32), dim3(32, 8), 0, stream>>>(x, Wq, Wkv, Wout, xh, Wqkvt, Wot);
    gemm_mn<0><<<dim3(64, 9), 256, 0, stream>>>(xh, Wqkvt, qh, kh, vt, nullptr, nullptr);
    attn_kernel<<<dim3(32, 32), 256, 0, stream>>>(qh, kh, vt, rel, ob);
    gemm_mn<2><<<dim3(64, 8), 256, 0, stream>>>(ob, Wot, nullptr, nullptr, nullptr, out, bout);
}

// Round 16
// 157.502 us; speedup vs baseline: 1.0184x; 1.0184x over previous
//
#include <hip/hip_runtime.h>
#include <cstdint>
#include <cmath>

typedef _Float16 half8 __attribute__((ext_vector_type(8)));
typedef unsigned short ushort8 __attribute__((ext_vector_type(8)));
typedef float floatx4 __attribute__((ext_vector_type(4)));

#define VT_STRIDE 2080  // 2048 + 32: breaks 4KB L2 set aliasing on V^T rows

__device__ __forceinline__ unsigned short f2h(float f) {
    union { _Float16 h; unsigned short u; } cv;
    cv.h = (_Float16)f;
    return cv.u;
}

// async global -> LDS, 16B per lane; LDS dest is wave-uniform base + lane*16
__device__ __forceinline__ void gld_lds16(const unsigned short* g, unsigned short* l) {
    __builtin_amdgcn_global_load_lds(
        (const __attribute__((address_space(1))) unsigned int*)g,
        (__attribute__((address_space(3))) unsigned int*)l, 16, 0, 0);
}

// ---------------- merged prep: cast x (fp32->fp16) + transpose+cast W matrices ----------------
__global__ void prep_kernel(const float* __restrict__ x,
                            const float* __restrict__ Wq, const float* __restrict__ Wkv,
                            const float* __restrict__ Wout,
                            unsigned short* __restrict__ xh,
                            unsigned short* __restrict__ Wqkvt, unsigned short* __restrict__ Wot) {
    int bxi = blockIdx.x;
    if (bxi >= 68) {
        int fb = (bxi - 68) * 32 + blockIdx.y;          // 0..2047
        int tt = threadIdx.y * 32 + threadIdx.x;        // 0..255
        int idx = fb * 256 + tt;                        // < 524288
        const float4* p = (const float4*)x;
        float4 a = p[idx * 2], b = p[idx * 2 + 1];
        ushort8 o;
        o[0] = f2h(a.x); o[1] = f2h(a.y); o[2] = f2h(a.z); o[3] = f2h(a.w);
        o[4] = f2h(b.x); o[5] = f2h(b.y); o[6] = f2h(b.z); o[7] = f2h(b.w);
        *(ushort8*)(xh + (size_t)idx * 8) = o;
        return;
    }
    __shared__ float tile[32][33];
    const float* in; unsigned short* out; int C; int cb;
    if (bxi < 32)      { in = Wq;   out = Wqkvt;                 C = 1024; cb = bxi; }
    else if (bxi < 36) { in = Wkv;  out = Wqkvt + 1024 * 1024;   C = 128;  cb = bxi - 32; }
    else               { in = Wout; out = Wot;                   C = 1024; cb = bxi - 36; }
    int bx = cb * 32, by = blockIdx.y * 32;
    int xx = threadIdx.x, y0 = threadIdx.y;
    #pragma unroll
    for (int k = 0; k < 4; k++) {
        int y = y0 + k * 8;
        tile[y][xx] = in[(size_t)(by + y) * C + bx + xx];
    }
    __syncthreads();
    #pragma unroll
    for (int k = 0; k < 4; k++) {
        int y = y0 + k * 8;
        out[(size_t)(bx + y) * 1024 + by + xx] = f2h(tile[xx][y]);
    }
}

// ---------------- GEMM 64M x 128N, K=1024 (R5/R8-measured best, byte-exact) ----------------
template<int MODE>
__global__ __launch_bounds__(256) void gemm_mn(
    const unsigned short* __restrict__ A, const unsigned short* __restrict__ Bt,
    unsigned short* __restrict__ oq, unsigned short* __restrict__ ok,
    unsigned short* __restrict__ ov, float* __restrict__ of,
    const float* __restrict__ bias)
{
    __shared__ __align__(16) unsigned short As[2][64 * 64];
    __shared__ __align__(16) unsigned short Bs[2][128 * 64];
    const int K = 1024;
    int t = threadIdx.x;
    int w = t >> 6, lane = t & 63, g = lane >> 4, il = lane & 15;
    int wr = w >> 1, wc = w & 1;
    int m0 = blockIdx.x * 64, n0 = blockIdx.y * 128;

    int l8 = lane >> 3, b8 = lane & 7;
    int swz = (b8 ^ l8) * 8;
    const unsigned short* Ag = A  + (size_t)(m0 + w * 16 + l8) * K + swz;
    const unsigned short* Bg = Bt + (size_t)(n0 + w * 32 + l8) * K + swz;
    int e0 = (g ^ (il & 7)) * 8;

    floatx4 acc[2][4] = {};

    #pragma unroll
    for (int q = 0; q < 2; q++)
        gld_lds16(Ag + (size_t)(q * 8) * K, &As[0][(w * 16 + q * 8) * 64]);
    #pragma unroll
    for (int q = 0; q < 4; q++)
        gld_lds16(Bg + (size_t)(q * 8) * K, &Bs[0][(w * 32 + q * 8) * 64]);

    int cb = 0;
    for (int k0 = 0; k0 < K; k0 += 64, cb ^= 1) {
        if (k0 + 64 < K) {
            #pragma unroll
            for (int q = 0; q < 2; q++)
                gld_lds16(Ag + (size_t)(q * 8) * K + k0 + 64, &As[cb ^ 1][(w * 16 + q * 8) * 64]);
            #pragma unroll
            for (int q = 0; q < 4; q++)
                gld_lds16(Bg + (size_t)(q * 8) * K + k0 + 64, &Bs[cb ^ 1][(w * 32 + q * 8) * 64]);
            asm volatile("s_waitcnt vmcnt(6)" ::: "memory");
        } else {
            asm volatile("s_waitcnt vmcnt(0)" ::: "memory");
        }
        __builtin_amdgcn_s_barrier();
        __builtin_amdgcn_sched_barrier(0);

        const unsigned short* Ac = &As[cb][0];
        const unsigned short* Bc = &Bs[cb][0];
        #pragma unroll
        for (int ks = 0; ks < 2; ks++) {
            half8 a[2];
            #pragma unroll
            for (int mt = 0; mt < 2; mt++)
                a[mt] = *(const half8*)&Ac[(wr * 32 + mt * 16 + il) * 64 + (e0 ^ (ks * 32))];
            #pragma unroll
            for (int nt = 0; nt < 4; nt++) {
                half8 b = *(const half8*)&Bc[(wc * 64 + nt * 16 + il) * 64 + (e0 ^ (ks * 32))];
                #pragma unroll
                for (int mt = 0; mt < 2; mt++)
                    acc[mt][nt] = __builtin_amdgcn_mfma_f32_16x16x32_f16(a[mt], b, acc[mt][nt], 0, 0, 0);
            }
        }
        asm volatile("s_waitcnt lgkmcnt(0)" ::: "memory");
        __builtin_amdgcn_s_barrier();
    }

    #pragma unroll
    for (int mt = 0; mt < 2; mt++) {
        #pragma unroll
        for (int nt = 0; nt < 4; nt++) {
            #pragma unroll
            for (int r = 0; r < 4; r++) {
                int row = m0 + wr * 32 + mt * 16 + 4 * g + r;
                int col = n0 + wc * 64 + nt * 16 + il;
                float v = acc[mt][nt][r];
                if (MODE == 0) {
                    if (col < 1024) {
                        int b = row >> 11, i = row & 2047, h = col >> 6, d = col & 63;
                        oq[(size_t)((b * 16 + h) * 2048 + i) * 64 + d] = f2h(v * 0.18033688011112042f);
                    } else if (col < 1088) {
                        ok[(size_t)row * 64 + (col - 1024)] = f2h(v);
                    } else {
                        int b = row >> 11, j = row & 2047;
                        ov[(size_t)((b << 6) + (col - 1088)) * VT_STRIDE + j] = f2h(v);
                    }
                } else {
                    of[(size_t)row * 1024 + col] = v + bias[col];
                }
            }
        }
    }
}

// ---------------- flash attention: R12 structure + far-field bias fold ----------------
// LDS 26624B, single-buffered K and V. Bias table stores (bucket - bucket31) so the
// far field (bucket saturated, ~13.5 of 16.5 chunks) adds exactly zero -- softmax is
// shift-invariant per row, verified passing in R4 (absmax identical). Rescale stays
// UNCONDITIONAL (R5 measured the conditional variant -6us).
__global__ __launch_bounds__(256) void attn_kernel(
    const unsigned short* __restrict__ qh, const unsigned short* __restrict__ kh,
    const unsigned short* __restrict__ vt, const float* __restrict__ rel_emb,
    unsigned short* __restrict__ ob)
{
    __shared__ float bias_tab[256];
    __shared__ __align__(16) unsigned short Ks[64 * 64];      // [j][d], single-buffered
    __shared__ __align__(16) unsigned short Vs[64 * 64];      // [d][j], single-buffered
    __shared__ __align__(16) unsigned short Pl[64 * 72];      // wave-private P rows

    int yy = blockIdx.y;
    int jp = yy & 7, sp = yy >> 3;   // balanced tile permutation
    int bx = (sp == 0) ? (31 - jp) : (sp == 1) ? jp : (sp == 2) ? (23 - jp) : (8 + jp);
    int bh = blockIdx.x;
    int b = bh >> 4, h = bh & 15;
    int t = threadIdx.x;
    int w = t >> 6, lane = t & 63, g = lane >> 4, il = lane & 15;

    // bias' table: far-field constant folded out (uniform per-row shift cancels in softmax)
    float cbv = rel_emb[31 * 16 + h];
    {
        int dlt = t;
        int bucket;
        if (dlt < 16) bucket = dlt;
        else {
            float lg = logf((float)dlt * 0.0625f) / 2.0794415416798357f;
            int vv = 16 + (int)(lg * 16.0f);
            bucket = vv < 31 ? vv : 31;
        }
        bias_tab[dlt] = (rel_emb[bucket * 16 + h] - cbv) * 11.541560327111708f;
    }

    const unsigned short* kbase = kh + (size_t)b * (2048 * 64);
    const unsigned short* vbase = vt + (size_t)b * (64 * VT_STRIDE);
    int prow = (w * 16 + il) * 72;

    int l8 = lane >> 3, b8 = lane & 7;
    int swz = (b8 ^ l8) * 8;
    const unsigned short* kg_base = kbase + (size_t)(w * 16 + l8) * 64 + swz;
    const unsigned short* vg_base = vbase + (size_t)(w * 16 + l8) * VT_STRIDE + swz;
    int e0 = (g ^ (il & 7)) * 8;

    int iw = bx * 64 + w * 16;
    int i_glob = iw + il;
    const unsigned short* qrow = qh + (size_t)(bh * 2048 + i_glob) * 64;
    half8 qf0 = *(const half8*)(qrow + g * 8);
    half8 qf1 = *(const half8*)(qrow + 32 + g * 8);
    floatx4 O[4] = {};
    float m_run = -1e30f, l_run = 0.0f;

    // prologue: stage chunk 0
    gld_lds16(kg_base,                 &Ks[(w * 16) * 64]);
    gld_lds16(kg_base + 8 * 64,        &Ks[(w * 16 + 8) * 64]);
    gld_lds16(vg_base,                 &Vs[(w * 16) * 64]);
    gld_lds16(vg_base + 8 * VT_STRIDE, &Vs[(w * 16 + 8) * 64]);

    for (int c = 0; c <= bx; c++) {
        __syncthreads();   // drains vmcnt(0): K(c)+V(c) staged; lgkm: prior Pl reads retired
        int j0 = c * 64;

        // S^T = K.Q^T from single K buffer
        floatx4 S[4] = {};
        #pragma unroll
        for (int jt = 0; jt < 4; jt++) {
            half8 k0 = *(const half8*)&Ks[jt * 1024 + il * 64 + e0];
            half8 k1 = *(const half8*)&Ks[jt * 1024 + il * 64 + (e0 ^ 32)];
            S[jt] = __builtin_amdgcn_mfma_f32_16x16x32_f16(k0, qf0, S[jt], 0, 0, 0);
            S[jt] = __builtin_amdgcn_mfma_f32_16x16x32_f16(k1, qf1, S[jt], 0, 0, 0);
        }
        // V fragments -> registers
        half8 vf[8];
        #pragma unroll
        for (int ks = 0; ks < 2; ks++)
            #pragma unroll
            for (int dt = 0; dt < 4; dt++)
                vf[ks * 4 + dt] = *(const half8*)&Vs[dt * 1024 + il * 64 + (e0 ^ (ks * 32))];

        // all reads of Ks/Vs retired across the block -> safe to overwrite
        asm volatile("s_waitcnt lgkmcnt(0)" ::: "memory");
        __builtin_amdgcn_s_barrier();
        if (c < bx) {      // stage K(c+1)+V(c+1); DMA flies under softmax+pack+PV
            const unsigned short* kg = kg_base + (size_t)(c + 1) * 4096;
            const unsigned short* vg = vg_base + (c + 1) * 64;
            gld_lds16(kg,                 &Ks[(w * 16) * 64]);
            gld_lds16(kg + 8 * 64,        &Ks[(w * 16 + 8) * 64]);
            gld_lds16(vg,                 &Vs[(w * 16) * 64]);
            gld_lds16(vg + 8 * VT_STRIDE, &Vs[(w * 16 + 8) * 64]);
        }

        float s[16];
        if (c + 3 <= bx) {
            // far field: folded bias is exactly zero
            #pragma unroll
            for (int q2 = 0; q2 < 16; q2++) s[q2] = S[q2 >> 2][q2 & 3];
        } else if (c < bx) {
            #pragma unroll
            for (int jt = 0; jt < 4; jt++)
                #pragma unroll
                for (int r = 0; r < 4; r++)
                    s[jt * 4 + r] = S[jt][r] + bias_tab[i_glob - (j0 + jt * 16 + 4 * g + r)];
        } else {
            #pragma unroll
            for (int jt = 0; jt < 4; jt++) {
                #pragma unroll
                for (int r = 0; r < 4; r++) {
                    int delta = i_glob - (j0 + jt * 16 + 4 * g + r);
                    int di = delta > 0 ? delta : 0;
                    s[jt * 4 + r] = (delta >= 0) ? (S[jt][r] + bias_tab[di]) : -1e30f;
                }
            }
        }
        // online softmax (exp2 domain), tree reductions, unconditional rescale
        float m8[8];
        #pragma unroll
        for (int q2 = 0; q2 < 8; q2++) m8[q2] = fmaxf(s[q2], s[q2 + 8]);
        #pragma unroll
        for (int q2 = 0; q2 < 4; q2++) m8[q2] = fmaxf(m8[q2], m8[q2 + 4]);
        float mx = fmaxf(fmaxf(m8[0], m8[1]), fmaxf(m8[2], m8[3]));
        mx = fmaxf(mx, __shfl_xor(mx, 16));
        mx = fmaxf(mx, __shfl_xor(mx, 32));
        float m_new = fmaxf(m_run, mx);
        float alpha = __builtin_amdgcn_exp2f(m_run - m_new);
        float p[16];
        #pragma unroll
        for (int q2 = 0; q2 < 16; q2++) p[q2] = __builtin_amdgcn_exp2f(s[q2] - m_new);
        float ps[8];
        #pragma unroll
        for (int q2 = 0; q2 < 8; q2++) ps[q2] = p[q2] + p[q2 + 8];
        #pragma unroll
        for (int q2 = 0; q2 < 4; q2++) ps[q2] += ps[q2 + 4];
        float psum = (ps[0] + ps[1]) + (ps[2] + ps[3]);
        psum += __shfl_xor(psum, 16);
        psum += __shfl_xor(psum, 32);
        l_run = l_run * alpha + psum;
        m_run = m_new;
        float arow[4];
        #pragma unroll
        for (int r = 0; r < 4; r++) arow[r] = __shfl(alpha, 4 * g + r);
        #pragma unroll
        for (int dt = 0; dt < 4; dt++)
            #pragma unroll
            for (int r = 0; r < 4; r++) O[dt][r] *= arow[r];

        #pragma unroll
        for (int jt = 0; jt < 4; jt++) {
            uint2 u;
            u.x = (unsigned int)f2h(p[jt * 4 + 0]) | ((unsigned int)f2h(p[jt * 4 + 1]) << 16);
            u.y = (unsigned int)f2h(p[jt * 4 + 2]) | ((unsigned int)f2h(p[jt * 4 + 3]) << 16);
            *(uint2*)&Pl[prow + jt * 16 + 4 * g] = u;
        }
        #pragma unroll
        for (int ks = 0; ks < 2; ks++) {
            half8 pf = *(const half8*)&Pl[prow + ks * 32 + g * 8];
            #pragma unroll
            for (int dt = 0; dt < 4; dt++)
                O[dt] = __builtin_amdgcn_mfma_f32_16x16x32_f16(pf, vf[ks * 4 + dt], O[dt], 0, 0, 0);
        }
    }
    // epilogue: normalize, store [b*2048+i][h*64+d] fp16
    float inv[4];
    #pragma unroll
    for (int r = 0; r < 4; r++) inv[r] = 1.0f / __shfl(l_run, 4 * g + r);
    #pragma unroll
    for (int dt = 0; dt < 4; dt++) {
        #pragma unroll
        for (int r = 0; r < 4; r++) {
            int i = iw + 4 * g + r;
            int d = dt * 16 + il;
            ob[(size_t)(b * 2048 + i) * 1024 + h * 64 + d] = f2h(O[dt][r] * inv[r]);
        }
    }
}

extern "C" void kernel_launch(void* const* d_in, const int* in_sizes, int n_in,
                              void* d_out, int out_size, void* d_ws, size_t ws_size,
                              hipStream_t stream) {
    const float* x    = (const float*)d_in[0];
    const float* Wq   = (const float*)d_in[1];
    const float* Wkv  = (const float*)d_in[2];
    const float* Wout = (const float*)d_in[3];
    const float* bout = (const float*)d_in[4];
    const float* rel  = (const float*)d_in[5];
    float* out = (float*)d_out;

    unsigned short* ws    = (unsigned short*)d_ws;
    unsigned short* xh    = ws;                      // [4096][1024] fp16 x; reused as attn out
    unsigned short* qh    = xh + 4194304;            // [b,h,i,d] fp16, exp2-domain prescaled
    unsigned short* kh    = qh + 4194304;            // [b*2048+j][64]
    unsigned short* vt    = kh + 262144;             // [b][64][VT_STRIDE] padded V^T
    unsigned short* Wqkvt = vt + 2 * 64 * VT_STRIDE; // [1152][1024]
    unsigned short* Wot   = Wqkvt + 1179648;         // [1024][1024]
    unsigned short* ob    = xh;

    prep_kernel<<<dim3(132, 32), dim3(32, 8), 0, stream>>>(x, Wq, Wkv, Wout, xh, Wqkvt, Wot);
    gemm_mn<0><<<dim3(64, 9), 256, 0, stream>>>(xh, Wqkvt, qh, kh, vt, nullptr, nullptr);
    attn_kernel<<<dim3(32, 32), 256, 0, stream>>>(qh, kh, vt, rel, ob);
    gemm_mn<2><<<dim3(64, 8), 256, 0, stream>>>(ob, Wot, nullptr, nullptr, nullptr, out, bout);
}